// Round 5
// baseline (122.107 us; speedup 1.0000x reference)
//
#include <hip/hip_runtime.h>
#include <hip/hip_bf16.h>

// ExplicitInterClassGraphLoss on MI355X (gfx950)
//   loss = mean_{i,j} (fn_i . fn_j - zg[lbl_i, lbl_j])^2,  fn = row-normalized feat
// R5 = R4 resubmitted (infra timeout, no measurement):
// 256x256 tile pairs, BK=32, 8 waves (2Mx4N), triple-buffered LDS,
// 2 phases/K-tile with counted vmcnt(4) (T3+T4), setprio around MFMA (T5),
// chunk-XOR LDS swizzle (T2, both-sides), XCD-aware block swizzle (T1).
// Pipeline ledger (per wave, FIFO vmcnt semantics):
//   prologue: issue t0(A,B), t1(A,B) -> vmcnt(4) ensures t0; barrier.
//   tile t: P1 issues A(t+2), P2 issues B(t+2); boundary vmcnt(4) leaves
//   t+2's 4 loads in flight, guarantees all of t+1. Triple buffer (t%3)
//   makes t+2's writes land in a buffer not read since tile t-1. Tail:
//   t=NT-2 boundary vmcnt(0) drains t=NT-1's loads.

typedef __attribute__((ext_vector_type(8))) short bf16x8;
typedef __attribute__((ext_vector_type(4))) float f32x4;

#define NROW 8192
#define DIM  512
#define NBIN 40
#define NBLK 32                    // 8192 / 256
#define NPAIR (NBLK*(NBLK+1)/2)    // 528
#define BK 32
#define NT (DIM/BK)                // 16 K-tiles
#define TELEM (256*BK)             // elems per tile buffer

__device__ __forceinline__ unsigned short f2bf(float x) {
  __hip_bfloat16 h = __float2bfloat16(x);
  union { __hip_bfloat16 h; unsigned short u; } cv;
  cv.h = h;
  return cv.u;
}

// ---------------- kernel 1: row L2-normalize, fp32 -> bf16 ----------------
__global__ __launch_bounds__(256) void rownorm_kernel(const float* __restrict__ feat,
                                                      __hip_bfloat16* __restrict__ fn) {
  int wid  = threadIdx.x >> 6;
  int lane = threadIdx.x & 63;
  int row  = blockIdx.x * 4 + wid;
  const float4* src = (const float4*)(feat + (size_t)row * DIM);
  float4 a = src[lane];
  float4 b = src[lane + 64];
  float s = a.x*a.x + a.y*a.y + a.z*a.z + a.w*a.w
          + b.x*b.x + b.y*b.y + b.z*b.z + b.w*b.w;
#pragma unroll
  for (int off = 1; off < 64; off <<= 1) s += __shfl_xor(s, off, 64);
  float scale = 1.0f / fmaxf(sqrtf(s), 1e-8f);
  ushort4 o0, o1;
  o0.x = f2bf(a.x * scale); o0.y = f2bf(a.y * scale);
  o0.z = f2bf(a.z * scale); o0.w = f2bf(a.w * scale);
  o1.x = f2bf(b.x * scale); o1.y = f2bf(b.y * scale);
  o1.z = f2bf(b.z * scale); o1.w = f2bf(b.w * scale);
  ushort4* dst = (ushort4*)(fn + (size_t)row * DIM);
  dst[lane]      = o0;
  dst[lane + 64] = o1;
}

// ---------------- kernel 2: fused loss over one 256x256 tile pair ----------------
__global__ __launch_bounds__(512, 2) void loss_kernel(const __hip_bfloat16* __restrict__ fn,
                                                      const int* __restrict__ label,
                                                      double* __restrict__ partials) {
  __shared__ __hip_bfloat16 Abuf[3][TELEM];   // 3 x 16 KiB
  __shared__ __hip_bfloat16 Bbuf[3][TELEM];   // 3 x 16 KiB
  __shared__ float zg[NBIN * NBIN];
  __shared__ int   lbl[512];
  __shared__ float wsum[8];

  const int tid  = threadIdx.x;
  const int wid  = tid >> 6;
  const int lane = tid & 63;
  const int wm   = wid >> 2;   // 0..1 -> 128-row slab
  const int wn   = wid & 3;    // 0..3 -> 64-col slab

  // XCD-aware swizzle: 528 = 8 * 66 exactly -> simple form is bijective
  const int t0 = (blockIdx.x & 7) * (NPAIR / 8) + (blockIdx.x >> 3);

  // upper-triangular pair map (bi <= bj)
  int bi = 0;
  while (bi < NBLK - 1 && (bi + 1) * NBLK - ((bi + 1) * bi) / 2 <= t0) bi++;
  const int bj = bi + (t0 - (bi * NBLK - (bi * (bi - 1)) / 2));
  const int i0 = bi * 256;
  const int j0 = bj * 256;

  // zg table + labels (consumed only in epilogue; writer waves drain their
  // ds_writes at the first lgkmcnt(0); epilogue is many barriers later)
  for (int idx = tid; idx < NBIN * NBIN; idx += 512) {
    int a = idx / NBIN, b = idx - a * NBIN;
    float d = fabsf((float)(a - b)) * (float)(1.5707963267948966 / (NBIN - 1));
    zg[idx] = fminf(fmaxf(cosf(d), 0.0f), 1.0f);
  }
  lbl[tid] = (tid < 256) ? label[i0 + tid] : label[j0 + tid - 256];

  // staging geometry: tile = 256 rows x 32 cols = 1024 16B-chunks; 2/thread.
  // LDS chunk L -> (row=L>>2, c=L&3); slot holds global chunk c ^ ((row>>1)&3)
  // (involution; read side applies the same XOR). Dest is linear in lane order.
  const __hip_bfloat16* srcA[2];
  const __hip_bfloat16* srcB[2];
  int dstOff[2];
#pragma unroll
  for (int q = 0; q < 2; ++q) {
    const int L   = tid + q * 512;
    const int row = L >> 2;
    const int cg  = (L & 3) ^ ((row >> 1) & 3);
    srcA[q] = fn + (size_t)(i0 + row) * DIM + cg * 8;
    srcB[q] = fn + (size_t)(j0 + row) * DIM + cg * 8;
    dstOff[q] = (q * 512 + wid * 64) * 16;   // bytes; wave-uniform base
  }

  auto issueA = [&](int tt, int bb) {
#pragma unroll
    for (int q = 0; q < 2; ++q)
      __builtin_amdgcn_global_load_lds(
          (const __attribute__((address_space(1))) void*)(srcA[q] + tt * BK),
          (__attribute__((address_space(3))) void*)((char*)&Abuf[bb][0] + dstOff[q]),
          16, 0, 0);
  };
  auto issueB = [&](int tt, int bb) {
#pragma unroll
    for (int q = 0; q < 2; ++q)
      __builtin_amdgcn_global_load_lds(
          (const __attribute__((address_space(1))) void*)(srcB[q] + tt * BK),
          (__attribute__((address_space(3))) void*)((char*)&Bbuf[bb][0] + dstOff[q]),
          16, 0, 0);
  };

  // ---- prologue: tiles 0 and 1 in flight; ensure tile 0 ----
  issueA(0, 0); issueB(0, 0);
  issueA(1, 1); issueB(1, 1);
  asm volatile("s_waitcnt vmcnt(4)" ::: "memory");   // tile 0 (oldest 4) done
  __builtin_amdgcn_s_barrier();

  f32x4 acc[8][4] = {};
  const int fr = lane & 15;                 // fragment row-in-16
  const int fc = lane >> 4;                 // fragment k-chunk 0..3
  const int cx = fc ^ ((fr >> 1) & 3);      // swizzled chunk (row>>1 mod 4 == fr>>1 mod 4)
  const int arow0 = wm * 128 + fr;
  const int brow0 = wn * 64 + fr;

  int rb = 0;   // t % 3
  for (int t = 0; t < NT; ++t) {
    const __hip_bfloat16* Ab = &Abuf[rb][0];
    const __hip_bfloat16* Bb = &Bbuf[rb][0];
    const int pb = (rb >= 1) ? rb - 1 : rb + 2;   // (t+2) % 3

    // ---- phase 1: frags for mf0-3 + all B; issue A(t+2) ----
    bf16x8 a0[4], bv[4];
#pragma unroll
    for (int mf = 0; mf < 4; ++mf)
      a0[mf] = *(const bf16x8*)&Ab[(arow0 + mf * 16) * BK + cx * 8];
#pragma unroll
    for (int nf = 0; nf < 4; ++nf)
      bv[nf] = *(const bf16x8*)&Bb[(brow0 + nf * 16) * BK + cx * 8];
    if (t < NT - 2) issueA(t + 2, pb);
    __builtin_amdgcn_s_barrier();
    asm volatile("s_waitcnt lgkmcnt(0)" ::: "memory");
    __builtin_amdgcn_s_setprio(1);
#pragma unroll
    for (int mf = 0; mf < 4; ++mf)
#pragma unroll
      for (int nf = 0; nf < 4; ++nf)
        acc[mf][nf] = __builtin_amdgcn_mfma_f32_16x16x32_bf16(a0[mf], bv[nf], acc[mf][nf], 0, 0, 0);
    __builtin_amdgcn_s_setprio(0);
    __builtin_amdgcn_s_barrier();

    // ---- phase 2: frags for mf4-7 (B reused in regs); issue B(t+2) ----
    bf16x8 a1[4];
#pragma unroll
    for (int mf = 0; mf < 4; ++mf)
      a1[mf] = *(const bf16x8*)&Ab[(arow0 + 64 + mf * 16) * BK + cx * 8];
    if (t < NT - 2) issueB(t + 2, pb);
    __builtin_amdgcn_s_barrier();
    asm volatile("s_waitcnt lgkmcnt(0)" ::: "memory");
    __builtin_amdgcn_s_setprio(1);
#pragma unroll
    for (int mf = 0; mf < 4; ++mf)
#pragma unroll
      for (int nf = 0; nf < 4; ++nf)
        acc[4 + mf][nf] = __builtin_amdgcn_mfma_f32_16x16x32_bf16(a1[mf], bv[nf], acc[4 + mf][nf], 0, 0, 0);
    __builtin_amdgcn_s_setprio(0);

    // ---- tile boundary: counted wait (never 0 in steady state) ----
    if (t < NT - 2)       asm volatile("s_waitcnt vmcnt(4)" ::: "memory"); // tile t+1 landed
    else if (t == NT - 2) asm volatile("s_waitcnt vmcnt(0)" ::: "memory"); // drain tile t+1 (last)
    __builtin_amdgcn_s_barrier();
    rb = (rb + 1 >= 3) ? 0 : rb + 1;
  }

  // ---- epilogue: diff vs zg, sum of squares ----
  // C/D mapping (m89): col = lane&15 (= fr), row = (lane>>4)*4 + r. Transpose-safe.
  const int rb4 = (lane >> 4) * 4;
  int ljv[4];
#pragma unroll
  for (int nf = 0; nf < 4; ++nf) ljv[nf] = lbl[256 + wn * 64 + nf * 16 + fr];
  float lsum = 0.0f;
#pragma unroll
  for (int mf = 0; mf < 8; ++mf) {
#pragma unroll
    for (int r = 0; r < 4; ++r) {
      const int li = lbl[wm * 128 + mf * 16 + rb4 + r];
      const float* zrow = &zg[li * NBIN];
#pragma unroll
      for (int nf = 0; nf < 4; ++nf) {
        float d = acc[mf][nf][r] - zrow[ljv[nf]];
        lsum += d * d;
      }
    }
  }
  if (bi != bj) lsum *= 2.0f;   // off-diagonal tile counted twice

#pragma unroll
  for (int off = 1; off < 64; off <<= 1) lsum += __shfl_xor(lsum, off, 64);
  if (lane == 0) wsum[wid] = lsum;
  __syncthreads();
  if (tid == 0) {
    double s = 0.0;
#pragma unroll
    for (int w = 0; w < 8; ++w) s += (double)wsum[w];
    partials[blockIdx.x] = s;
  }
}

// ---------------- kernel 3: finalize ----------------
__global__ __launch_bounds__(256) void finalize_kernel(const double* __restrict__ partials,
                                                       int nblk, float* __restrict__ out) {
  __shared__ double wsh[4];
  int wid = threadIdx.x >> 6, lane = threadIdx.x & 63;
  double s = 0.0;
  for (int i = threadIdx.x; i < nblk; i += 256) s += partials[i];
#pragma unroll
  for (int off = 1; off < 64; off <<= 1) s += __shfl_xor(s, off, 64);
  if (lane == 0) wsh[wid] = s;
  __syncthreads();
  if (threadIdx.x == 0) {
    double tot = wsh[0] + wsh[1] + wsh[2] + wsh[3];
    out[0] = (float)(tot / ((double)NROW * (double)NROW));
  }
}

extern "C" void kernel_launch(void* const* d_in, const int* in_sizes, int n_in,
                              void* d_out, int out_size, void* d_ws, size_t ws_size,
                              hipStream_t stream) {
  const int*   label = (const int*)d_in[0];    // (8192,) int32
  const float* feat  = (const float*)d_in[1];  // (8192, 512) fp32
  float* out = (float*)d_out;

  char* ws = (char*)d_ws;
  __hip_bfloat16* fn = (__hip_bfloat16*)ws;                       // 8 MiB
  double* partials = (double*)(ws + (size_t)NROW * DIM * 2);      // NPAIR doubles

  rownorm_kernel<<<NROW / 4, 256, 0, stream>>>(feat, fn);
  loss_kernel<<<NPAIR, 512, 0, stream>>>(fn, label, partials);
  finalize_kernel<<<1, 256, 0, stream>>>(partials, NPAIR, out);
}

// Round 6
// 116.034 us; speedup vs baseline: 1.0523x; 1.0523x over previous
//
#include <hip/hip_runtime.h>
#include <hip/hip_bf16.h>

// ExplicitInterClassGraphLoss on MI355X (gfx950)
//   loss = mean_{i,j} (fn_i . fn_j - zg[lbl_i, lbl_j])^2,  fn = row-normalized feat
// R6: occupancy-first redesign. 128x128 tile pairs (2080), 4 waves of 64x64
// (acc=64 regs -> ~116 total -> 4 waves/SIMD via __launch_bounds__(256,4)),
// double-buffered LDS (33 KB -> 4 blocks/CU), depth-1 prefetch with ONE
// barrier per K-tile, chunk-XOR swizzle (T2), setprio (T5), XCD swizzle (T1).
// zg replaced by 40-entry zd[|li-lj|] table.
// Ledger (per tile t, buf c=t&1): reads from c (plain ds_read -> MFMA dep);
//   issue t+1 into c^1 (WAR: c^1's readers finished before t-1's end barrier,
//   issue is after it); lgkm0 -> MFMA; vmcnt(0) drains t+1's 4 loads (issued
//   ~1 tile earlier, latency hidden); s_barrier makes t+1 visible block-wide.

typedef __attribute__((ext_vector_type(8))) short bf16x8;
typedef __attribute__((ext_vector_type(4))) float f32x4;

#define NROW 8192
#define DIM  512
#define NBIN 40
#define NBLK 64                    // 8192 / 128
#define NPAIR (NBLK*(NBLK+1)/2)    // 2080
#define BK 32
#define NT (DIM/BK)                // 16 K-tiles
#define TELEM (128*BK)             // 4096 elems = 8 KiB per tile buffer

__device__ __forceinline__ unsigned short f2bf(float x) {
  __hip_bfloat16 h = __float2bfloat16(x);
  union { __hip_bfloat16 h; unsigned short u; } cv;
  cv.h = h;
  return cv.u;
}

// ---------------- kernel 1: row L2-normalize, fp32 -> bf16 ----------------
__global__ __launch_bounds__(256) void rownorm_kernel(const float* __restrict__ feat,
                                                      __hip_bfloat16* __restrict__ fn) {
  int wid  = threadIdx.x >> 6;
  int lane = threadIdx.x & 63;
  int row  = blockIdx.x * 4 + wid;
  const float4* src = (const float4*)(feat + (size_t)row * DIM);
  float4 a = src[lane];
  float4 b = src[lane + 64];
  float s = a.x*a.x + a.y*a.y + a.z*a.z + a.w*a.w
          + b.x*b.x + b.y*b.y + b.z*b.z + b.w*b.w;
#pragma unroll
  for (int off = 1; off < 64; off <<= 1) s += __shfl_xor(s, off, 64);
  float scale = 1.0f / fmaxf(sqrtf(s), 1e-8f);
  ushort4 o0, o1;
  o0.x = f2bf(a.x * scale); o0.y = f2bf(a.y * scale);
  o0.z = f2bf(a.z * scale); o0.w = f2bf(a.w * scale);
  o1.x = f2bf(b.x * scale); o1.y = f2bf(b.y * scale);
  o1.z = f2bf(b.z * scale); o1.w = f2bf(b.w * scale);
  ushort4* dst = (ushort4*)(fn + (size_t)row * DIM);
  dst[lane]      = o0;
  dst[lane + 64] = o1;
}

// ---------------- kernel 2: fused loss over one 128x128 tile pair ----------------
__global__ __launch_bounds__(256, 4) void loss_kernel(const __hip_bfloat16* __restrict__ fn,
                                                      const int* __restrict__ label,
                                                      double* __restrict__ partials) {
  __shared__ __hip_bfloat16 Abuf[2][TELEM];   // 2 x 8 KiB
  __shared__ __hip_bfloat16 Bbuf[2][TELEM];   // 2 x 8 KiB
  __shared__ float zd[NBIN];                  // zd[d] = clip(cos(d*pi/2/39),0,1)
  __shared__ int   lbl[256];
  __shared__ float wsum[4];

  const int tid  = threadIdx.x;
  const int wid  = tid >> 6;
  const int lane = tid & 63;
  const int wr   = wid >> 1;   // 0..1 -> 64-row slab
  const int wc   = wid & 1;    // 0..1 -> 64-col slab

  // XCD-aware swizzle: 2080 = 8 * 260 exactly -> bijective
  const int t0 = (blockIdx.x & 7) * (NPAIR / 8) + (blockIdx.x >> 3);

  // upper-triangular pair map (bi <= bj)
  int bi = 0;
  while (bi < NBLK - 1 && (bi + 1) * NBLK - ((bi + 1) * bi) / 2 <= t0) bi++;
  const int bj = bi + (t0 - (bi * NBLK - (bi * (bi - 1)) / 2));
  const int i0 = bi * 128;
  const int j0 = bj * 128;

  // 40-entry distance table + labels (drained by tile-0's lgkmcnt(0) + barriers)
  if (tid < NBIN) {
    float d = (float)tid * (float)(1.5707963267948966 / (NBIN - 1));
    zd[tid] = fminf(fmaxf(cosf(d), 0.0f), 1.0f);
  }
  lbl[tid] = (tid < 128) ? label[i0 + tid] : label[j0 + tid - 128];

  // staging geometry: tile = 128 rows x 32 cols = 512 16B-chunks; 2/thread.
  // LDS chunk L -> (row=L>>2, c=L&3); slot holds global chunk c ^ ((row>>1)&3)
  // (involution; read side applies same XOR). Dest linear in lane order.
  const __hip_bfloat16* srcA[2];
  const __hip_bfloat16* srcB[2];
  int dstOff[2];
#pragma unroll
  for (int q = 0; q < 2; ++q) {
    const int L   = q * 256 + tid;
    const int row = L >> 2;
    const int cg  = (L & 3) ^ ((row >> 1) & 3);
    srcA[q] = fn + (size_t)(i0 + row) * DIM + cg * 8;
    srcB[q] = fn + (size_t)(j0 + row) * DIM + cg * 8;
    dstOff[q] = (q * 256 + wid * 64) * 16;   // bytes; wave-uniform base
  }

  auto issueTile = [&](int tt, int bb) {
#pragma unroll
    for (int q = 0; q < 2; ++q)
      __builtin_amdgcn_global_load_lds(
          (const __attribute__((address_space(1))) void*)(srcA[q] + tt * BK),
          (__attribute__((address_space(3))) void*)((char*)&Abuf[bb][0] + dstOff[q]),
          16, 0, 0);
#pragma unroll
    for (int q = 0; q < 2; ++q)
      __builtin_amdgcn_global_load_lds(
          (const __attribute__((address_space(1))) void*)(srcB[q] + tt * BK),
          (__attribute__((address_space(3))) void*)((char*)&Bbuf[bb][0] + dstOff[q]),
          16, 0, 0);
  };

  // ---- prologue: tile 0 into buf 0 ----
  issueTile(0, 0);
  asm volatile("s_waitcnt vmcnt(0)" ::: "memory");
  __builtin_amdgcn_s_barrier();

  f32x4 acc[4][4] = {};
  const int fr = lane & 15;                 // fragment row-in-16
  const int fc = lane >> 4;                 // fragment k-chunk 0..3
  const int cx = fc ^ ((fr >> 1) & 3);      // swizzled chunk
  const int arow0 = wr * 64 + fr;
  const int brow0 = wc * 64 + fr;

  for (int t = 0; t < NT; ++t) {
    const int c = t & 1;
    const __hip_bfloat16* Ab = &Abuf[c][0];
    const __hip_bfloat16* Bb = &Bbuf[c][0];

    bf16x8 af[4], bf[4];
#pragma unroll
    for (int m = 0; m < 4; ++m)
      af[m] = *(const bf16x8*)&Ab[(arow0 + m * 16) * BK + cx * 8];
#pragma unroll
    for (int n = 0; n < 4; ++n)
      bf[n] = *(const bf16x8*)&Bb[(brow0 + n * 16) * BK + cx * 8];

    if (t < NT - 1) issueTile(t + 1, c ^ 1);   // depth-1 prefetch into other buffer

    asm volatile("s_waitcnt lgkmcnt(0)" ::: "memory");
    __builtin_amdgcn_s_setprio(1);
#pragma unroll
    for (int m = 0; m < 4; ++m)
#pragma unroll
      for (int n = 0; n < 4; ++n)
        acc[m][n] = __builtin_amdgcn_mfma_f32_16x16x32_bf16(af[m], bf[n], acc[m][n], 0, 0, 0);
    __builtin_amdgcn_s_setprio(0);

    if (t < NT - 1) {
      asm volatile("s_waitcnt vmcnt(0)" ::: "memory");  // t+1 landed (hidden under MFMA)
      __builtin_amdgcn_s_barrier();                     // block-wide visibility
    }
  }

  // ---- epilogue: diff vs zd[|li-lj|], sum of squares ----
  // C/D mapping (m89): col = lane&15, row = (lane>>4)*4 + r. Transpose-safe
  // (both matrices symmetric).
  const int rb4 = (lane >> 4) * 4;
  int ljv[4];
#pragma unroll
  for (int n = 0; n < 4; ++n) ljv[n] = lbl[128 + wc * 64 + n * 16 + fr];
  float lsum = 0.0f;
#pragma unroll
  for (int m = 0; m < 4; ++m) {
#pragma unroll
    for (int r = 0; r < 4; ++r) {
      const int li = lbl[wr * 64 + m * 16 + rb4 + r];
#pragma unroll
      for (int n = 0; n < 4; ++n) {
        int dd = li - ljv[n]; if (dd < 0) dd = -dd;
        float d = acc[m][n][r] - zd[dd];
        lsum += d * d;
      }
    }
  }
  if (bi != bj) lsum *= 2.0f;   // off-diagonal tile counted twice

#pragma unroll
  for (int off = 1; off < 64; off <<= 1) lsum += __shfl_xor(lsum, off, 64);
  if (lane == 0) wsum[wid] = lsum;
  __syncthreads();
  if (tid == 0)
    partials[blockIdx.x] = (double)((wsum[0] + wsum[1]) + (wsum[2] + wsum[3]));
}

// ---------------- kernel 3: finalize ----------------
__global__ __launch_bounds__(256) void finalize_kernel(const double* __restrict__ partials,
                                                       int nblk, float* __restrict__ out) {
  __shared__ double wsh[4];
  int wid = threadIdx.x >> 6, lane = threadIdx.x & 63;
  double s = 0.0;
  for (int i = threadIdx.x; i < nblk; i += 256) s += partials[i];
#pragma unroll
  for (int off = 1; off < 64; off <<= 1) s += __shfl_xor(s, off, 64);
  if (lane == 0) wsh[wid] = s;
  __syncthreads();
  if (threadIdx.x == 0) {
    double tot = wsh[0] + wsh[1] + wsh[2] + wsh[3];
    out[0] = (float)(tot / ((double)NROW * (double)NROW));
  }
}

extern "C" void kernel_launch(void* const* d_in, const int* in_sizes, int n_in,
                              void* d_out, int out_size, void* d_ws, size_t ws_size,
                              hipStream_t stream) {
  const int*   label = (const int*)d_in[0];    // (8192,) int32
  const float* feat  = (const float*)d_in[1];  // (8192, 512) fp32
  float* out = (float*)d_out;

  char* ws = (char*)d_ws;
  __hip_bfloat16* fn = (__hip_bfloat16*)ws;                       // 8 MiB
  double* partials = (double*)(ws + (size_t)NROW * DIM * 2);      // NPAIR doubles

  rownorm_kernel<<<NROW / 4, 256, 0, stream>>>(feat, fn);
  loss_kernel<<<NPAIR, 256, 0, stream>>>(fn, label, partials);
  finalize_kernel<<<1, 256, 0, stream>>>(partials, NPAIR, out);
}